// Round 2
// 565.857 us; speedup vs baseline: 1.0989x; 1.0989x over previous
//
#include <hip/hip_runtime.h>
#include <math.h>

#define B_ 32
#define C_ 256
#define HW_ 96
#define G_ 2
#define K_ 3
#define CR_ 64
#define IMG_ (HW_*HW_)       // 9216 floats per (b,c) image
#define BN_EPS 1e-5f

typedef float vfloat4 __attribute__((ext_vector_type(4)));  // native vec for nontemporal builtin

// ---------------------------------------------------------------------------
// Kernel 1: adaptive avg-pool to 3x3.  grid = B*C*3 (one WG per block-row),
// block = 256.  Coalesced float4 loads; 3 column-bin predicated accumulate;
// wave shuffle reduce + tiny LDS reduce.  Reads x FORWARD so the tail of x
// is L3-resident when dwconv (reversed) starts.
// ---------------------------------------------------------------------------
__global__ __launch_bounds__(256) void pool_kernel(const float* __restrict__ x,
                                                   float* __restrict__ pooled) {
    int wg = blockIdx.x;
    int bh = wg % 3;          // block-row index (rows bh*32 .. bh*32+31)
    int bc = wg / 3;          // b*C + c
    const float4* src = (const float4*)(x + (size_t)bc * IMG_ + (size_t)bh * 32 * HW_);
    int t = threadIdx.x;
    float a0 = 0.f, a1 = 0.f, a2 = 0.f;
    #pragma unroll
    for (int k = 0; k < 3; ++k) {
        int f = t + 256 * k;               // float4 index in [0, 768)
        float4 v = src[f];
        float s = v.x + v.y + v.z + v.w;
        int colq = f % 24;                 // 24 float4s per row
        int bin = colq >> 3;               // 8 quads per 32-wide column block
        a0 += (bin == 0) ? s : 0.f;
        a1 += (bin == 1) ? s : 0.f;
        a2 += (bin == 2) ? s : 0.f;
    }
    #pragma unroll
    for (int off = 32; off > 0; off >>= 1) {
        a0 += __shfl_down(a0, off);
        a1 += __shfl_down(a1, off);
        a2 += __shfl_down(a2, off);
    }
    __shared__ float red[3][4];
    int wave = t >> 6, lane = t & 63;
    if (lane == 0) { red[0][wave] = a0; red[1][wave] = a1; red[2][wave] = a2; }
    __syncthreads();
    if (t < 3) {
        float s = red[t][0] + red[t][1] + red[t][2] + red[t][3];
        pooled[(size_t)bc * 9 + bh * 3 + t] = s * (1.0f / 1024.0f);  // 32*32 pixels
    }
}

// ---------------------------------------------------------------------------
// Kernel 2: projection MLP + softmax mixing.
// REGRIDDED: grid = (10 pos, B) = 320 WGs (was 32 -> 12.5% of CUs, latency
// bound).  Each WG handles one (b, pos): pos 0..8 = 3x3 pooled positions,
// pos 9 = global-avg-pool.  Layer 1 uses 4 lanes per output + shfl_xor
// reduce; chunked so sub-lane LDS addresses are only 2-way on a bank (free).
// ---------------------------------------------------------------------------
__global__ __launch_bounds__(256) void proj_kernel(
    const float* __restrict__ pooled,   // [B*C, 9]
    const float* __restrict__ dyn_w,    // [G, C, 9]
    const float* __restrict__ dyn_b,    // [G, C]
    const float* __restrict__ w1,       // [CR, C]
    const float* __restrict__ bn_g, const float* __restrict__ bn_b,
    const float* __restrict__ bn_m, const float* __restrict__ bn_v,
    const float* __restrict__ w2,       // [C*G, CR]
    const float* __restrict__ b2,       // [C*G]
    float* __restrict__ wout,           // [B*C, 9]
    float* __restrict__ bout)           // [B*C]
{
    int pos = blockIdx.x;               // 0..9
    int b   = blockIdx.y;               // 0..B-1
    int t   = threadIdx.x;

    __shared__ float spool[C_];         // pooled value at this pos, per channel
    __shared__ float sh[CR_];           // hidden activations

    // stage this (b, pos) column of pooled features
    {
        const float* p = pooled + ((size_t)b * C_ + t) * 9;
        float v;
        if (pos < 9) {
            v = p[pos];
        } else {                        // gap = mean of the 9 block means
            float s = 0.f;
            #pragma unroll
            for (int i = 0; i < 9; ++i) s += p[i];
            v = s * (1.0f / 9.0f);
        }
        spool[t] = v;
    }
    __syncthreads();

    // layer 1: h = GELU(BN(w1 @ spool)).  64 outputs, 4 lanes each.
    {
        int o = t >> 2, sub = t & 3;
        const float* wrow = w1 + (size_t)o * C_;
        float acc = 0.f;
        #pragma unroll
        for (int cc = 0; cc < 4; ++cc) {
            int base = cc * 64 + sub * 16;       // sub offsets {0,16,32,48}: 2-way banks
            const float4* wq = (const float4*)(wrow + base);
            const float* pp = spool + base;
            #pragma unroll
            for (int i = 0; i < 4; ++i) {
                float4 wv = wq[i];
                acc += wv.x * pp[4*i]   + wv.y * pp[4*i+1]
                     + wv.z * pp[4*i+2] + wv.w * pp[4*i+3];
            }
        }
        acc += __shfl_xor(acc, 1);
        acc += __shfl_xor(acc, 2);
        if (sub == 0) {
            float inv = bn_g[o] * rsqrtf(bn_v[o] + BN_EPS);
            float hv = acc * inv + (bn_b[o] - bn_m[o] * inv);
            hv = 0.5f * hv * (1.0f + erff(hv * 0.70710678118654752f));
            sh[o] = hv;
        }
    }
    __syncthreads();

    // layer 2: s = w2 @ h + b2, softmax over G=2, mix dynamic banks.  c = t.
    {
        int c = t;
        const float4* r0 = (const float4*)(w2 + (size_t)c * CR_);          // g=0
        const float4* r1 = (const float4*)(w2 + (size_t)(C_ + c) * CR_);   // g=1
        float s0 = b2[c], s1 = b2[C_ + c];
        #pragma unroll
        for (int i = 0; i < CR_ / 4; ++i) {
            float4 v0 = r0[i], v1 = r1[i];
            float h0 = sh[4*i], h1 = sh[4*i+1], h2 = sh[4*i+2], h3 = sh[4*i+3];
            s0 += v0.x*h0 + v0.y*h1 + v0.z*h2 + v0.w*h3;
            s1 += v1.x*h0 + v1.y*h1 + v1.z*h2 + v1.w*h3;
        }
        float m = fmaxf(s0, s1);
        float e0 = expf(s0 - m), e1 = expf(s1 - m);
        float p0 = e0 / (e0 + e1), p1 = 1.0f - p0;
        if (pos < 9) {
            wout[((size_t)b * C_ + c) * 9 + pos] =
                p0 * dyn_w[(size_t)c * 9 + pos] + p1 * dyn_w[(size_t)(C_ * 9) + c * 9 + pos];
        } else {
            bout[(size_t)b * C_ + c] = p0 * dyn_b[c] + p1 * dyn_b[C_ + c];
        }
    }
}

// ---------------------------------------------------------------------------
// Kernel 3: per-(b,c) depthwise 3x3 conv (pad 1) + bias.
// NO LDS: register sliding window.  grid = B*C, block = 192 (3 waves).
// REVERSED bc order: pool streamed x forward, so the TAIL of x is still
// resident in the 256 MB Infinity Cache -- consume it first.
// NONTEMPORAL stores (via native ext_vector_type): out is never re-read;
// don't let the 302 MB write stream evict x from L2/L3.
// ---------------------------------------------------------------------------
__global__ __launch_bounds__(192) void dwconv_kernel(const float* __restrict__ x,
                                                     const float* __restrict__ wgt,
                                                     const float* __restrict__ bias,
                                                     float* __restrict__ out) {
    int bc = (B_ * C_ - 1) - blockIdx.x;   // reverse order for L3 reuse of x tail
    int t = threadIdx.x;
    int qc = t % 24;            // quad column 0..23
    int rg = t / 24;            // row group 0..7
    int r0 = rg * 12;

    const float* img = x + (size_t)bc * IMG_;
    vfloat4* dst = (vfloat4*)(out + (size_t)bc * IMG_);

    float w[9];
    #pragma unroll
    for (int i = 0; i < 9; ++i) w[i] = wgt[(size_t)bc * 9 + i];
    float bs = bias[bc];

    float A[6], Bv[6], Cv[6];   // rows r-1, r, r+1; cols 4qc-1 .. 4qc+4

    // loadrow: fills d[0..5] with img[r][4qc-1 .. 4qc+4] (zeros outside)
    #define LOADROW(r, d)                                                    \
        do {                                                                 \
            int _r = (r);                                                    \
            if ((unsigned)_r < (unsigned)HW_) {                              \
                const float* _p = img + _r * HW_ + 4 * qc;                   \
                float4 _v = *(const float4*)_p;                              \
                d[1] = _v.x; d[2] = _v.y; d[3] = _v.z; d[4] = _v.w;          \
                d[0] = (qc > 0)  ? _p[-1] : 0.f;                             \
                d[5] = (qc < 23) ? _p[4]  : 0.f;                             \
            } else {                                                         \
                d[0] = d[1] = d[2] = d[3] = d[4] = d[5] = 0.f;               \
            }                                                                \
        } while (0)

    LOADROW(r0 - 1, A);
    LOADROW(r0,     Bv);

    #pragma unroll
    for (int i = 0; i < 12; ++i) {
        int r = r0 + i;
        LOADROW(r + 1, Cv);
        vfloat4 o;
        o.x = bs; o.y = bs; o.z = bs; o.w = bs;
        #pragma unroll
        for (int j = 0; j < 3; ++j) {
            o.x += A[j]  * w[j] + Bv[j]  * w[3+j] + Cv[j]  * w[6+j];
            o.y += A[j+1]* w[j] + Bv[j+1]* w[3+j] + Cv[j+1]* w[6+j];
            o.z += A[j+2]* w[j] + Bv[j+2]* w[3+j] + Cv[j+2]* w[6+j];
            o.w += A[j+3]* w[j] + Bv[j+3]* w[3+j] + Cv[j+3]* w[6+j];
        }
        __builtin_nontemporal_store(o, &dst[r * 24 + qc]);
        #pragma unroll
        for (int j = 0; j < 6; ++j) { A[j] = Bv[j]; Bv[j] = Cv[j]; }
    }
    #undef LOADROW
}

// ---------------------------------------------------------------------------
extern "C" void kernel_launch(void* const* d_in, const int* in_sizes, int n_in,
                              void* d_out, int out_size, void* d_ws, size_t ws_size,
                              hipStream_t stream) {
    const float* x     = (const float*)d_in[0];
    const float* dyn_w = (const float*)d_in[1];
    const float* dyn_b = (const float*)d_in[2];
    const float* w1    = (const float*)d_in[3];
    const float* bn_g  = (const float*)d_in[4];
    const float* bn_b  = (const float*)d_in[5];
    const float* bn_m  = (const float*)d_in[6];
    const float* bn_v  = (const float*)d_in[7];
    const float* w2    = (const float*)d_in[8];
    const float* b2    = (const float*)d_in[9];
    float* out = (float*)d_out;

    float* ws = (float*)d_ws;
    float* pooled = ws;                        // [B*C, 9]  = 73728 floats
    float* weight = ws + (size_t)B_ * C_ * 9;  // [B*C, 9]  = 73728 floats
    float* bias   = weight + (size_t)B_ * C_ * 9;  // [B*C] = 8192 floats

    pool_kernel<<<B_ * C_ * 3, 256, 0, stream>>>(x, pooled);
    proj_kernel<<<dim3(10, B_), 256, 0, stream>>>(pooled, dyn_w, dyn_b, w1, bn_g, bn_b,
                                                  bn_m, bn_v, w2, b2, weight, bias);
    dwconv_kernel<<<B_ * C_, 192, 0, stream>>>(x, weight, bias, out);
}